// Round 1
// baseline (295.453 us; speedup 1.0000x reference)
//
#include <hip/hip_runtime.h>
#include <math.h>

#define NB 8
#define DET 512
#define NA 180
#define SDIM 512

// ws float layout:
//   [0, 360)      : CS table, (255.5*cos, 255.5*sin) interleaved per angle
//   [512, 1536)   : G2 table, G2[i] = g(|i-512|), 1024 entries
//   [2048, 2048+NB*NA*DET) : xsT, filtered sinogram, layout [b][a][d]
#define WS_CS 0
#define WS_G2 512
#define WS_XST 2048

// ---------------- prep: angle + filter tables ----------------
__global__ void prep_kernel(float* __restrict__ ws) {
    const int t = threadIdx.x;
    if (t < NA) {
        float th = (float)t * 0.017453292519943295f;
        ws[WS_CS + 2 * t]     = 255.5f * cosf(th);
        ws[WS_CS + 2 * t + 1] = 255.5f * sinf(th);
    }
    const double PI = 3.14159265358979323846;
    for (int i = t; i < 1024; i += 512) {
        int k = i - 512; if (k < 0) k = -k;
        float g;
        if (k == 0)       g = 0.5f;
        else if (k & 1)   g = (float)(-2.0 / (PI * PI * (double)k * (double)k));
        else              g = 0.0f;
        ws[WS_G2 + i] = g;
    }
}

// ---------------- filter: direct convolution ----------------
// grid = 8 b * 45 a-groups (4 angles each); block = 256 (one wave per column)
// lane l computes 8 consecutive outputs d = 8l .. 8l+7
__global__ __launch_bounds__(256) void filter_kernel(const float* __restrict__ x,
                                                     float* __restrict__ ws) {
    __shared__ float xcol[4][DET];
    __shared__ float g2s[1024];

    const int b  = blockIdx.x / 45;
    const int a0 = (blockIdx.x % 45) * 4;
    const int t  = threadIdx.x;

    for (int i = t; i < 1024; i += 256) g2s[i] = ws[WS_G2 + i];
    // stage 4 columns of x: x[b][j][a0+al], input layout (b,1,det,angle)
    for (int i = t; i < 4 * DET; i += 256) {
        int j = i >> 2, al = i & 3;
        xcol[al][j] = x[(b * DET + j) * NA + a0 + al];
    }
    __syncthreads();

    const int al = t >> 6;          // wave -> column
    const int d0 = (t & 63) << 3;   // 8 outputs per lane

    float acc[8];
#pragma unroll
    for (int r = 0; r < 8; ++r) acc[r] = 0.0f;

    const float* xc = &xcol[al][0];
    for (int j0 = 0; j0 < DET; j0 += 4) {
        // g window: G2[s-4 .. s+7], s = 512 + d0 - j0 (multiple of 4)
        int s4 = 512 + d0 - j0 - 4;
        float win[12];
        *(float4*)(win)     = *(const float4*)(g2s + s4);
        *(float4*)(win + 4) = *(const float4*)(g2s + s4 + 4);
        *(float4*)(win + 8) = *(const float4*)(g2s + s4 + 8);
        float xv[4];
        *(float4*)(xv) = *(const float4*)(xc + j0);
#pragma unroll
        for (int jj = 0; jj < 4; ++jj) {
#pragma unroll
            for (int r = 0; r < 8; ++r) {
                acc[r] = fmaf(xv[jj], win[4 + r - jj], acc[r]);
            }
        }
    }

    float* xsT = ws + WS_XST;
    size_t base = ((size_t)(b * NA + a0 + al) << 9) + d0;
    *(float4*)(xsT + base)     = make_float4(acc[0], acc[1], acc[2], acc[3]);
    *(float4*)(xsT + base + 4) = make_float4(acc[4], acc[5], acc[6], acc[7]);
}

// ---------------- backprojection ----------------
// grid = 8 b * 256 tiles (16x16 grid of 32x32-pixel tiles); block = 256
// wave = 8x8 pixel patch (clustered LDS gather addresses -> broadcast-friendly)
// LDS columns have 128-word zero guards: idx = floor(yi)+128 in [22,745], no bounds checks.
#define CHUNK 15
#define COLW 768
__global__ __launch_bounds__(256, 3) void backproj_kernel(const float* __restrict__ ws,
                                                          float* __restrict__ out) {
    __shared__ float cols[CHUNK][COLW];   // 45 KB
    __shared__ float cst[2 * NA];         // 1.4 KB

    const int b    = blockIdx.x >> 8;
    const int tile = blockIdx.x & 255;
    const int x0 = (tile & 15) * 32;
    const int y0 = (tile >> 4) * 32;
    const int t  = threadIdx.x;

    const int px = t & 7;
    const int py = (t >> 3) & 7;
    const int qx = (t >> 6) & 1;
    const int qy = (t >> 7) & 1;

    // thread's 4 pixels: (2 x-values) x (2 y-values)
    int xi[2], yi_[2];
    float xg[2], yg[2];
#pragma unroll
    for (int i = 0; i < 2; ++i) {
        xi[i]  = x0 + px + 8 * qx + 16 * i;
        yi_[i] = y0 + py + 8 * qy + 16 * i;
        xg[i] = (float)(2 * xi[i]  - 511) * (1.0f / 511.0f);
        yg[i] = (float)(2 * yi_[i] - 511) * (1.0f / 511.0f);
    }

    for (int i = t; i < 2 * NA; i += 256) cst[i] = ws[WS_CS + i];

    const float* xsT = ws + WS_XST;
    float acc[2][2] = {{0.0f, 0.0f}, {0.0f, 0.0f}};

    for (int c = 0; c < 12; ++c) {
        __syncthreads();   // previous chunk's readers done
        // stage CHUNK columns as float4 with zero guards
        for (int i4 = t; i4 < CHUNK * (COLW / 4); i4 += 256) {
            int ci = i4 / (COLW / 4);
            int r4 = i4 - ci * (COLW / 4);
            float4 v = make_float4(0.0f, 0.0f, 0.0f, 0.0f);
            if (r4 >= 32 && r4 < 160) {
                int a = c * CHUNK + ci;
                v = *(const float4*)(xsT + (((size_t)(b * NA + a)) << 9) + (r4 - 32) * 4);
            }
            *(float4*)(&cols[ci][r4 * 4]) = v;
        }
        __syncthreads();

        for (int ci = 0; ci < CHUNK; ++ci) {
            const int a = c * CHUNK + ci;
            const float C = cst[2 * a];
            const float S = cst[2 * a + 1];
            float ux[2], sy[2];
#pragma unroll
            for (int i = 0; i < 2; ++i) {
                ux[i] = fmaf(xg[i], C, 255.5f);
                sy[i] = yg[i] * S;
            }
            const float* colp = &cols[ci][0];
#pragma unroll
            for (int iy = 0; iy < 2; ++iy) {
#pragma unroll
                for (int ix = 0; ix < 2; ++ix) {
                    float yv = ux[ix] - sy[iy];
                    float fi = floorf(yv);
                    int   idx = (int)fi + 128;
                    float w  = yv - fi;
                    float v0 = colp[idx];
                    float v1 = colp[idx + 1];
                    acc[iy][ix] += v0 + w * (v1 - v0);
                }
            }
        }
    }

    const float scale = 0.008726646259971648f;  // pi / 360
#pragma unroll
    for (int iy = 0; iy < 2; ++iy) {
#pragma unroll
        for (int ix = 0; ix < 2; ++ix) {
            float r2 = xg[ix] * xg[ix] + yg[iy] * yg[iy];
            float val = (r2 <= 1.0f) ? acc[iy][ix] * scale : 0.0f;
            out[((size_t)b << 18) + ((size_t)yi_[iy] << 9) + xi[ix]] = val;
        }
    }
}

extern "C" void kernel_launch(void* const* d_in, const int* in_sizes, int n_in,
                              void* d_out, int out_size, void* d_ws, size_t ws_size,
                              hipStream_t stream) {
    const float* x = (const float*)d_in[0];
    float* out = (float*)d_out;
    float* ws  = (float*)d_ws;

    prep_kernel<<<1, 512, 0, stream>>>(ws);
    filter_kernel<<<NB * 45, 256, 0, stream>>>(x, ws);
    backproj_kernel<<<NB * 256, 256, 0, stream>>>(ws, out);
}

// Round 2
// 182.338 us; speedup vs baseline: 1.6204x; 1.6204x over previous
//
#include <hip/hip_runtime.h>
#include <math.h>

#define NB 8
#define DET 512
#define NA 180

// ws layout: xsT filtered sinogram at offset 0, [b][a][d], 8*180*512 floats (2.95 MB)

// ---------------- filter: direct convolution, j-split across 4 waves ----------------
// grid = 8 b * 180 a = 1440 blocks; block 256 (4 waves). Wave w handles j in [128w,128w+128).
// lane computes 8 consecutive outputs d = 8*(t&63).. ; partials reduced through LDS.
__global__ __launch_bounds__(256) void filter_kernel(const float* __restrict__ x,
                                                     float* __restrict__ ws) {
    __shared__ float xcol[DET];
    __shared__ float g2s[1024];
    __shared__ float part[4][DET];

    const int b = blockIdx.x / NA;
    const int a = blockIdx.x % NA;
    const int t = threadIdx.x;

    // build ramp-filter taps in LDS (g2s[i] = g(|i-512|))
    for (int i = t; i < 1024; i += 256) {
        int k = i - 512; if (k < 0) k = -k;
        float g = 0.0f;
        if (k == 0)      g = 0.5f;
        else if (k & 1)  { float fk = (float)k; g = -0.20264236728467558f / (fk * fk); }
        g2s[i] = g;
    }
    // stage column x[b][j][a]
    for (int i = t; i < DET; i += 256) xcol[i] = x[(b * DET + i) * NA + a];
    __syncthreads();

    const int w  = t >> 6;
    const int d0 = (t & 63) << 3;

    float acc[8];
#pragma unroll
    for (int r = 0; r < 8; ++r) acc[r] = 0.0f;

    const int jbeg = w << 7, jend = jbeg + 128;
    for (int j0 = jbeg; j0 < jend; j0 += 4) {
        int s4 = 512 + d0 - j0 - 4;     // multiple of 4 -> aligned float4 reads
        float win[12];
        *(float4*)(win)     = *(const float4*)(g2s + s4);
        *(float4*)(win + 4) = *(const float4*)(g2s + s4 + 4);
        *(float4*)(win + 8) = *(const float4*)(g2s + s4 + 8);
        float xv[4];
        *(float4*)(xv) = *(const float4*)(xcol + j0);
#pragma unroll
        for (int jj = 0; jj < 4; ++jj) {
#pragma unroll
            for (int r = 0; r < 8; ++r)
                acc[r] = fmaf(xv[jj], win[4 + r - jj], acc[r]);
        }
    }
    *(float4*)(&part[w][d0])     = make_float4(acc[0], acc[1], acc[2], acc[3]);
    *(float4*)(&part[w][d0 + 4]) = make_float4(acc[4], acc[5], acc[6], acc[7]);
    __syncthreads();

    // reduce 4 partials, 2 outputs per thread
    const int o = t << 1;
    float s0 = part[0][o]     + part[1][o]     + part[2][o]     + part[3][o];
    float s1 = part[0][o + 1] + part[1][o + 1] + part[2][o + 1] + part[3][o + 1];
    float* xsT = ws;
    size_t base = ((size_t)(b * NA + a) << 9) + o;
    xsT[base]     = s0;
    xsT[base + 1] = s1;
}

// ---------------- backprojection: batch-shared, windowed LDS staging ----------------
// grid = 1024 tiles (32x32 grid of 16x16-pixel tiles); block 256, 1 pixel/thread, 8 batches/thread.
// Per (tile,angle) the column footprint is <= 23 cells -> stage 32-entry windows.
// win[ci][b][33]: stride-33 padding -> conflict-free; v0/v1 = one ds_read2_b32 (imm offsets 33b, 33b+1).
#define CHUNK 20
__global__ __launch_bounds__(256, 4) void backproj_kernel(const float* __restrict__ ws,
                                                          float* __restrict__ out) {
    __shared__ float  win[CHUNK][8][33];   // 21.1 KB
    __shared__ float4 ang[NA];             // {bias = 255.5 - w0, C, S, pad}
    __shared__ int    w0i[NA];

    const int tile = blockIdx.x;
    const int x0 = (tile & 31) << 4;
    const int y0 = (tile >> 5) << 4;
    const int t  = threadIdx.x;
    const int px = t & 15, py = t >> 4;

    const float xg = (float)(2 * (x0 + px) - 511) * (1.0f / 511.0f);
    const float yg = (float)(2 * (y0 + py) - 511) * (1.0f / 511.0f);

    // per-block angle tables: C,S and window base from tile-corner min
    if (t < NA) {
        float th = (float)t * 0.017453292519943295f;
        float C = 255.5f * cosf(th);
        float S = 255.5f * sinf(th);
        float xga = (float)(2 * x0 - 511)        * (1.0f / 511.0f);
        float xgb = (float)(2 * (x0 + 15) - 511) * (1.0f / 511.0f);
        float yga = (float)(2 * y0 - 511)        * (1.0f / 511.0f);
        float ygb = (float)(2 * (y0 + 15) - 511) * (1.0f / 511.0f);
        float mn = 255.5f + fminf(xga * C, xgb * C) + fminf(-yga * S, -ygb * S);
        int w0 = (int)floorf(mn) - 1;
        w0i[t] = w0;
        ang[t] = make_float4(255.5f - (float)w0, C, S, 0.0f);
    }

    const float* xsT = ws;
    float acc[8];
#pragma unroll
    for (int b = 0; b < 8; ++b) acc[b] = 0.0f;

    for (int c = 0; c < NA / CHUNK; ++c) {
        __syncthreads();   // tables ready (c=0) / previous chunk's readers done
        // stage CHUNK angle-windows, all 8 batches; lanes 0..31 cover off 0..31 (coalesced)
        for (int i = t; i < CHUNK * 256; i += 256) {
            int ci  = i >> 8;
            int r   = i & 255;
            int b   = r >> 5;
            int off = r & 31;
            int a   = c * CHUNK + ci;
            int d   = w0i[a] + off;
            float v = 0.0f;
            if ((unsigned)d < 512u)
                v = xsT[(((size_t)(b * NA + a)) << 9) + d];
            win[ci][b][off] = v;
        }
        __syncthreads();

#pragma unroll 2
        for (int ci = 0; ci < CHUNK; ++ci) {
            float4 A = ang[c * CHUNK + ci];
            float yv = fmaf(-yg, A.z, fmaf(xg, A.y, A.x));   // window-relative position
            float fi = floorf(yv);
            int  off = (int)fi;
            float wgt = yv - fi;
            float wm  = 1.0f - wgt;
            const float* wp = &win[ci][0][off];
#pragma unroll
            for (int b = 0; b < 8; ++b) {
                float v0 = wp[b * 33];
                float v1 = wp[b * 33 + 1];
                acc[b] = fmaf(v0, wm, fmaf(v1, wgt, acc[b]));
            }
        }
    }

    const float r2 = xg * xg + yg * yg;
    const float m  = (r2 <= 1.0f) ? 0.008726646259971648f : 0.0f;  // pi/360 masked
    const size_t pbase = ((size_t)(y0 + py) << 9) + (size_t)(x0 + px);
#pragma unroll
    for (int b = 0; b < 8; ++b)
        out[((size_t)b << 18) + pbase] = acc[b] * m;
}

extern "C" void kernel_launch(void* const* d_in, const int* in_sizes, int n_in,
                              void* d_out, int out_size, void* d_ws, size_t ws_size,
                              hipStream_t stream) {
    const float* x = (const float*)d_in[0];
    float* out = (float*)d_out;
    float* ws  = (float*)d_ws;

    filter_kernel<<<NB * NA, 256, 0, stream>>>(x, ws);
    backproj_kernel<<<1024, 256, 0, stream>>>(ws, out);
}

// Round 3
// 149.492 us; speedup vs baseline: 1.9764x; 1.2197x over previous
//
#include <hip/hip_runtime.h>
#include <hip/hip_fp16.h>
#include <math.h>

#define NB 8
#define DET 512
#define NA 180
#define TILES 1024                    // 32x32 grid of 16x16-pixel tiles

// ws layout (32-bit words):
//  [0, TANG_WORDS)              : tang float4 per (tile,angle): {bias=255.5-w0, C, S, w0 int bits}
//  [TANG_WORDS, +XST_WORDS)     : xsT packed half2 sinogram, [a][d][b4], b4 = batch pair
#define TANG_WORDS (TILES * NA * 4)   // 737280  (2.95 MB)
#define XST_WORDS  (NA * DET * 4)     // 368640  (1.47 MB)

// ---------------- prep: per-(tile,angle) constants ----------------
__global__ __launch_bounds__(256) void prep_kernel(float4* __restrict__ tang) {
    int idx = blockIdx.x * 256 + threadIdx.x;
    if (idx >= TILES * NA) return;
    int tile = idx / NA;
    int a = idx - tile * NA;
    float th = (float)a * 0.017453292519943295f;
    float C = 255.5f * cosf(th);
    float S = 255.5f * sinf(th);
    int x0 = (tile & 31) << 4, y0 = (tile >> 5) << 4;
    float xga = (float)(2 * x0 - 511)        * (1.0f / 511.0f);
    float xgb = (float)(2 * (x0 + 15) - 511) * (1.0f / 511.0f);
    float yga = (float)(2 * y0 - 511)        * (1.0f / 511.0f);
    float ygb = (float)(2 * (y0 + 15) - 511) * (1.0f / 511.0f);
    // min over tile corners of yv = 255.5 + xg*C - yg*S  (linear -> extremum at corner)
    float mn = 255.5f + fminf(xga * C, xgb * C) + fminf(-yga * S, -ygb * S);
    int w0 = (int)floorf(mn) - 1;     // -1 slack: fma-vs-mul rounding differences
    tang[idx] = make_float4(255.5f - (float)w0, C, S, __int_as_float(w0));
}

// ---------------- filter: register sliding-window convolution ----------------
// grid = 180 (one angle, all 8 batches); block 256 = 4 waves.
// wave w: batches 2w,2w+1; lane: 32 lanes/batch, 16 consecutive outputs/lane.
// Tap window W[24] in registers slides by 8 -> LDS traffic 0.25 B/MAC.
__global__ __launch_bounds__(256) void filter_kernel(const float* __restrict__ x,
                                                     unsigned* __restrict__ xsT) {
    __shared__ float xcols[8][DET];   // 16 KB
    __shared__ float g2s[1024];       // 4 KB   g2s[i] = g(|i-512|)
    __shared__ float part[8][DET];    // 16 KB

    const int a = blockIdx.x;
    const int t = threadIdx.x;

    for (int i = t; i < 1024; i += 256) {
        int k = i - 512; if (k < 0) k = -k;
        float g = 0.0f;
        if (k == 0)      g = 0.5f;
        else if (k & 1)  { float fk = (float)k; g = -0.20264236728467558f / (fk * fk); }
        g2s[i] = g;
    }
    for (int i = t; i < 8 * DET; i += 256) {
        int b = i >> 9, j = i & 511;
        xcols[b][j] = x[(b * DET + j) * NA + a];
    }
    __syncthreads();

    const int w  = t >> 6, l = t & 63;
    const int b  = 2 * w + (l >> 5);
    const int d0 = (l & 31) << 4;

    float acc[16];
#pragma unroll
    for (int r = 0; r < 16; ++r) acc[r] = 0.0f;

    // W[i] = g2s[base + i], base(j0) = 504 + d0 - j0; FMA uses W[8 + r - jj]
    float W[24];
#pragma unroll
    for (int q = 0; q < 6; ++q)
        *(float4*)(W + 4 * q) = *(const float4*)(g2s + 504 + d0 + 4 * q);
    float xv[8];
    *(float4*)(xv)     = *(const float4*)(&xcols[b][0]);
    *(float4*)(xv + 4) = *(const float4*)(&xcols[b][4]);

    for (int j0 = 0; j0 < 512; j0 += 8) {
        float nxv[8], nW[8];
        const bool more = (j0 < 504);
        if (more) {   // prefetch next iteration's operands (hide LDS latency)
            *(float4*)(nxv)     = *(const float4*)(&xcols[b][j0 + 8]);
            *(float4*)(nxv + 4) = *(const float4*)(&xcols[b][j0 + 12]);
            *(float4*)(nW)      = *(const float4*)(g2s + 496 + d0 - j0);
            *(float4*)(nW + 4)  = *(const float4*)(g2s + 500 + d0 - j0);
        }
#pragma unroll
        for (int jj = 0; jj < 8; ++jj)
#pragma unroll
            for (int r = 0; r < 16; ++r)
                acc[r] = fmaf(xv[jj], W[8 + r - jj], acc[r]);
        if (more) {
#pragma unroll
            for (int i = 15; i >= 0; --i) W[i + 8] = W[i];
#pragma unroll
            for (int i = 0; i < 8; ++i) { W[i] = nW[i]; xv[i] = nxv[i]; }
        }
    }

#pragma unroll
    for (int q = 0; q < 4; ++q)
        *(float4*)(&part[b][d0 + 4 * q]) = *(const float4*)(acc + 4 * q);
    __syncthreads();

    // pack to half2 [a][d][b4], fully coalesced uint4 stores
    for (int i = t; i < DET; i += 256) {
        unsigned pk[4];
#pragma unroll
        for (int b4 = 0; b4 < 4; ++b4) {
            __half2 h2 = __halves2half2(__float2half_rn(part[2 * b4][i]),
                                        __float2half_rn(part[2 * b4 + 1][i]));
            pk[b4] = *(unsigned*)&h2;
        }
        *(uint4*)(xsT + ((size_t)a * DET + i) * 4) = make_uint4(pk[0], pk[1], pk[2], pk[3]);
    }
}

// ---------------- backprojection: half2 batch-packed windows ----------------
// grid = 1024 tiles; block 256, 1 pixel/thread, 8 batches/thread.
// win[ci][b4][33]: one ds_read2_b32 per batch-PAIR -> 4 LDS gathers per pixel-angle.
#define CHUNK 20
__global__ __launch_bounds__(256, 4) void backproj_kernel(const float4* __restrict__ tang,
                                                          const unsigned* __restrict__ xsT,
                                                          float* __restrict__ out) {
    __shared__ unsigned win[CHUNK][4][33];   // 10.56 KB

    const int tile = blockIdx.x;
    const int x0 = (tile & 31) << 4, y0 = (tile >> 5) << 4;
    const int t = threadIdx.x;
    const int px = t & 15, py = t >> 4;
    const float xg = (float)(2 * (x0 + px) - 511) * (1.0f / 511.0f);
    const float yg = (float)(2 * (y0 + py) - 511) * (1.0f / 511.0f);

    float acc[8];
#pragma unroll
    for (int b = 0; b < 8; ++b) acc[b] = 0.0f;

    const float4* ta = tang + (size_t)tile * NA;

    for (int c = 0; c < NA / CHUNK; ++c) {
        __syncthreads();   // previous chunk's readers done
        // stage CHUNK windows: coalesced uint4 global loads, scatter b32 to LDS
        for (int i = t; i < CHUNK * 32; i += 256) {
            int ci = i >> 5, off = i & 31;
            int a = c * CHUNK + ci;
            float4 A = ta[a];
            int d = __float_as_int(A.w) + off;   // w0 + off
            uint4 v = make_uint4(0u, 0u, 0u, 0u);
            if ((unsigned)d < 512u)
                v = *(const uint4*)(xsT + ((size_t)a * DET + d) * 4);
            win[ci][0][off] = v.x;
            win[ci][1][off] = v.y;
            win[ci][2][off] = v.z;
            win[ci][3][off] = v.w;
        }
        __syncthreads();

#pragma unroll 4
        for (int ci = 0; ci < CHUNK; ++ci) {
            float4 A = ta[c * CHUNK + ci];       // uniform index -> s_load_dwordx4
            float yv = fmaf(xg, A.y, A.x) - yg * A.z;  // window-relative position
            float fi = floorf(yv);
            int  off = (int)fi;
            __half2 w2 = __float2half2_rn(yv - fi);
            const unsigned* wp = &win[ci][0][off];
#pragma unroll
            for (int b4 = 0; b4 < 4; ++b4) {
                unsigned u0 = wp[33 * b4];
                unsigned u1 = wp[33 * b4 + 1];
                __half2 v0 = *(__half2*)&u0;
                __half2 v1 = *(__half2*)&u1;
                __half2 r  = __hfma2(w2, __hsub2(v1, v0), v0);
                float2  f  = __half22float2(r);
                acc[2 * b4]     += f.x;
                acc[2 * b4 + 1] += f.y;
            }
        }
    }

    const float r2 = xg * xg + yg * yg;
    const float m  = (r2 <= 1.0f) ? 0.008726646259971648f : 0.0f;  // pi/360 masked
    const size_t pbase = ((size_t)(y0 + py) << 9) + (size_t)(x0 + px);
#pragma unroll
    for (int b = 0; b < 8; ++b)
        out[((size_t)b << 18) + pbase] = acc[b] * m;
}

extern "C" void kernel_launch(void* const* d_in, const int* in_sizes, int n_in,
                              void* d_out, int out_size, void* d_ws, size_t ws_size,
                              hipStream_t stream) {
    const float* x = (const float*)d_in[0];
    float* out = (float*)d_out;
    float* ws  = (float*)d_ws;

    float4*   tang = (float4*)ws;
    unsigned* xsT  = (unsigned*)(ws + TANG_WORDS);

    prep_kernel<<<(TILES * NA + 255) / 256, 256, 0, stream>>>(tang);
    filter_kernel<<<NA, 256, 0, stream>>>(x, xsT);
    backproj_kernel<<<TILES, 256, 0, stream>>>(tang, xsT, out);
}